// Round 2
// baseline (71.276 us; speedup 1.0000x reference)
//
#include <hip/hip_runtime.h>

#define GG 1000
#define NPG 500
#define KK 8
#define N1 128
#define N2 128
#define NEG_SLOPE 0.45f
#define NTHREADS 512
#define NWAVES 8

__global__ __launch_bounds__(NTHREADS) void cluster_attn_kernel(
    const float* __restrict__ x,
    const float* __restrict__ W1,
    const float* __restrict__ b1,
    const float* __restrict__ Wa,
    const float* __restrict__ ba,
    const int*   __restrict__ cls,
    float*       __restrict__ out)
{
    __shared__ float s_acc[NWAVES][KK][N1];   // 32 KB; s_acc[0] becomes final csum
    __shared__ int   s_icnt[KK];
    __shared__ float s_fcnt[KK];
    __shared__ float s_ratio[KK];
    __shared__ float s_L[KK];
    __shared__ float s_e[KK];

    const int g    = blockIdx.x;
    const int tid  = threadIdx.x;
    const int w    = tid >> 6;     // wave 0..7
    const int l    = tid & 63;     // lane
    const int half = l >> 5;       // which node of the wave's pair
    const int fs   = l & 31;       // float4 slot (features fs*4 .. fs*4+3)

    const int* clsg = cls + (size_t)g * NPG;

    // ---- cluster counts via one-shot LDS atomics ----
    if (tid < KK) s_icnt[tid] = 0;
    __syncthreads();
    if (tid < NPG) atomicAdd(&s_icnt[clsg[tid]], 1);

    // ---- phase 1: register accumulation, predicated FMA (no LDS in loop) ----
    float acc[KK][4];
    #pragma unroll
    for (int k = 0; k < KK; ++k) {
        acc[k][0] = 0.f; acc[k][1] = 0.f; acc[k][2] = 0.f; acc[k][3] = 0.f;
    }

    const float4* x4 = (const float4*)(x + (size_t)g * NPG * N1);
    for (int n = w * 2; n < NPG; n += 2 * NWAVES) {
        int node = n + half;                    // lanes 0-31: node n, 32-63: n+1
        int c = clsg[node];                     // 2 distinct addrs/wave, L1-hot
        float4 v = x4[(size_t)node * 32 + fs];  // 1 KB coalesced per wave instr
        #pragma unroll
        for (int k = 0; k < KK; ++k) {
            float m = (c == k) ? 1.f : 0.f;
            acc[k][0] = fmaf(m, v.x, acc[k][0]);
            acc[k][1] = fmaf(m, v.y, acc[k][1]);
            acc[k][2] = fmaf(m, v.z, acc[k][2]);
            acc[k][3] = fmaf(m, v.w, acc[k][3]);
        }
    }

    // ---- combine the two node-halves, spill per-wave partial to LDS once ----
    #pragma unroll
    for (int k = 0; k < KK; ++k) {
        #pragma unroll
        for (int j = 0; j < 4; ++j)
            acc[k][j] += __shfl_xor(acc[k][j], 32);
    }
    if (l < 32) {
        #pragma unroll
        for (int k = 0; k < KK; ++k) {
            float4* dst = (float4*)&s_acc[w][k][0];
            dst[fs] = make_float4(acc[k][0], acc[k][1], acc[k][2], acc[k][3]);
        }
    }
    __syncthreads();

    // ---- reduce 8 wave partials into s_acc[0]; counts -> ratios ----
    float* accf = &s_acc[0][0][0];
    for (int e = tid; e < KK * N1; e += NTHREADS) {
        float s = 0.f;
        #pragma unroll
        for (int ww = 0; ww < NWAVES; ++ww) s += s_acc[ww][0][e];
        accf[e] = s;   // each thread overwrites only its own element: safe
    }
    if (tid == 0) {
        float d = 0.f;
        #pragma unroll
        for (int k = 0; k < KK; ++k) {
            float c = (float)s_icnt[k];
            s_fcnt[k] = c;
            d += c * c;                        // denom = sum_k c_k^2
        }
        #pragma unroll
        for (int k = 0; k < KK; ++k) s_ratio[k] = s_fcnt[k] / d;
    }
    __syncthreads();

    // ---- phase 2: h[k][j] = leaky(ratio_k*(csum_k . W1[:,j]) + b1[j]);
    //      hw[k][j] = h[k][j]*Wa[j]  (1024 dots over 512 threads) ----
    float* s_hw = &s_acc[1][0][0];             // reuse wave-copy 1 (1024 f32)
    #pragma unroll
    for (int r = 0; r < 2; ++r) {
        int idx = tid + r * NTHREADS;          // 0..1023
        int k = idx >> 7;
        int j = idx & 127;
        float s = 0.f;
        #pragma unroll 4
        for (int f = 0; f < N1; ++f)
            s = fmaf(accf[k * N1 + f], W1[f * N2 + j], s);  // LDS broadcast x coalesced W1
        float val = fmaf(s, s_ratio[k], b1[j]);
        float h = val > 0.f ? val : NEG_SLOPE * val;
        s_hw[idx] = h * Wa[j];
    }
    __syncthreads();

    // ---- per-k reduce: wave w owns cluster k=w ----
    {
        float v = s_hw[w * 128 + l] + s_hw[w * 128 + 64 + l];
        #pragma unroll
        for (int off = 32; off > 0; off >>= 1) v += __shfl_down(v, off);
        if (l == 0) s_L[w] = v + ba[0];
    }
    __syncthreads();

    // ---- phase 3: count-weighted softmax over 8 clusters (skip empty) ----
    if (tid == 0) {
        float m = -1e30f;
        #pragma unroll
        for (int k = 0; k < KK; ++k)
            if (s_fcnt[k] > 0.f) m = fmaxf(m, s_L[k]);
        float ssum = 0.f;
        float ek[KK];
        #pragma unroll
        for (int k = 0; k < KK; ++k) {
            ek[k] = (s_fcnt[k] > 0.f) ? expf(s_L[k] - m) : 0.f;
            ssum += s_fcnt[k] * ek[k];
        }
        #pragma unroll
        for (int k = 0; k < KK; ++k) s_e[k] = ek[k] / ssum;
    }
    __syncthreads();

    // ---- phase 4: per-node output = table lookup ----
    float* outg = out + (size_t)g * NPG;
    for (int n = tid; n < NPG; n += NTHREADS) outg[n] = s_e[clsg[n]];
}

extern "C" void kernel_launch(void* const* d_in, const int* in_sizes, int n_in,
                              void* d_out, int out_size, void* d_ws, size_t ws_size,
                              hipStream_t stream) {
    const float* x   = (const float*)d_in[0];
    const float* W1  = (const float*)d_in[1];
    const float* b1  = (const float*)d_in[2];
    const float* Wa  = (const float*)d_in[3];
    const float* ba  = (const float*)d_in[4];
    const int*   cls = (const int*)d_in[5];
    // d_in[6] = batch: sorted repeat(arange(G), NPG) by construction -> implicit

    float* out = (float*)d_out;
    cluster_attn_kernel<<<GG, NTHREADS, 0, stream>>>(x, W1, b1, Wa, ba, cls, out);
}